// Round 17
// baseline (65.108 us; speedup 1.0000x reference)
//
#include <hip/hip_runtime.h>
#include <hip/hip_bf16.h>

typedef unsigned short u16;
typedef unsigned int u32;
typedef __attribute__((ext_vector_type(8))) short short8;
typedef __attribute__((ext_vector_type(16))) float f32x16;

#define SEQ 2048

__device__ __forceinline__ u16 f2bf(float f) {
  union { __hip_bfloat16 h; u16 u; } c;
  c.h = __float2bfloat16(f);
  return c.u;
}

__device__ __forceinline__ float exp2fast(float x) {
  return __builtin_amdgcn_exp2f(x);  // v_exp_f32 (base-2)
}

// ---------------- fused prep ----------------
// z=0: Q -> ws [bh][seq][64] row-major (scaled).  z=1: K -> same (scaled).
// z=2: V -> fragment-linear V'[bh][sb32][ct*2+ks2][lane][8] (2 sb32-tiles per block).
// scale = 64^-0.25 * sqrt(log2 e)  (exp2-domain softmax)
__global__ __launch_bounds__(256) void prep_all(const float* __restrict__ qkv,
                                                u16* __restrict__ wsQ,
                                                u16* __restrict__ wsK,
                                                u16* __restrict__ wsV) {
  const int tid = threadIdx.x;
  const int bh = blockIdx.y;
  const int b = bh >> 3, h = bh & 7;
  const int z = blockIdx.z;

  if (z == 2) {
    // V-prep: block x covers tiles j = 2x, 2x+1
#pragma unroll
    for (int rep = 0; rep < 2; ++rep) {
      const int il = rep * 256 + tid;           // 0..511
      const int j = 2 * blockIdx.x + (il >> 8); // sb32 tile
      const int slot = il & 255;
      const int lane = slot & 63;
      const int ctks = slot >> 6;
      const int ct = ctks >> 1, ks2 = ctks & 1;
      const int hi = lane >> 5, tl = lane & 31;
      const int cc = ct * 32 + tl;
      const int s = j * 32 + ks2 * 16 + hi * 8;
      const float* src = qkv + ((size_t)b * 1536 + 1024 + (size_t)h * 64 + cc) * SEQ + s;
      const float4 v0 = *(const float4*)(src);
      const float4 v1 = *(const float4*)(src + 4);
      union { u16 us[8]; uint4 q; } pk;
      pk.us[0] = f2bf(v0.x); pk.us[1] = f2bf(v0.y); pk.us[2] = f2bf(v0.z); pk.us[3] = f2bf(v0.w);
      pk.us[4] = f2bf(v1.x); pk.us[5] = f2bf(v1.y); pk.us[6] = f2bf(v1.z); pk.us[7] = f2bf(v1.w);
      *(uint4*)(wsV + ((size_t)bh * 16384 + (size_t)j * 256 + slot) * 8) = pk.q;
    }
    return;
  }

  __shared__ float tile[64 * 67];
  const int t0 = blockIdx.x * 64;
  const int isK = z;
  const float scale = 0.42466090014692505f;
  const size_t inbase = ((size_t)b * 1536 + (size_t)isK * 512 + (size_t)h * 64) * SEQ;

  const int c = tid >> 2, tq = tid & 3;
#pragma unroll
  for (int u = 0; u < 4; ++u) {
    const int t = tq * 16 + u * 4;
    const float4 v = *(const float4*)(qkv + inbase + (size_t)c * SEQ + t0 + t);
    tile[c * 67 + t + 0] = v.x * scale;
    tile[c * 67 + t + 1] = v.y * scale;
    tile[c * 67 + t + 2] = v.z * scale;
    tile[c * 67 + t + 3] = v.w * scale;
  }
  __syncthreads();
  const int tt = tid >> 2, cq = tid & 3, c0 = cq * 16;
  u16* dst = (isK ? wsK : wsQ) + ((size_t)bh * SEQ + t0 + tt) * 64 + c0;
  union { u16 us[8]; uint4 v; } p0, p1;
#pragma unroll
  for (int i = 0; i < 8; ++i) p0.us[i] = f2bf(tile[(c0 + i) * 67 + tt]);
#pragma unroll
  for (int i = 0; i < 8; ++i) p1.us[i] = f2bf(tile[(c0 + 8 + i) * 67 + tt]);
  *(uint4*)(dst) = p0.v;
  *(uint4*)(dst + 8) = p1.v;
}

// ---------------- fused flash attention ----------------
// 256 thr = 4 waves = 2 s-half streams x 2 t-units; wave: QBLK=64 t, 1024 s (32 x 32-s tiles).
// K staged in LDS (4KB/stream/iter, XOR-swizzled, double-buffered, kg[2] only,
// load-early / write-mid, 1 barrier/iter). V fragments DIRECT from fragment-linear V'.
// Fixed-m softmax (p = exp2(S)); final /l = exact softmax.
// grid 512 (XCD-swizzled: 4 bh per XCD) -> 2-3 INDEPENDENT blocks/CU overlap barriers.
__global__ __launch_bounds__(256) void attn_kernel(const u16* __restrict__ wsQ,
                                                   const u16* __restrict__ wsK,
                                                   const u16* __restrict__ wsV,
                                                   float* __restrict__ out) {
  // main loop: stream sh owns [sh*8192, +8KB) = 2 x 4KB K double-buffer.
  // epilogue: reused as 2 x 16KB float partial slots (one per t-unit).
  __shared__ __align__(16) char smem[32768];
  __shared__ float Xl[2][2][32];  // [unit][cb][tl]

  const int tid = threadIdx.x;
  const int w = tid >> 6;
  const int lane = tid & 63;
  const int tl = lane & 31;
  const int hi = lane >> 5;
  const int sh = w >> 1;    // s-half stream
  const int u = w & 1;      // t-unit within block
  const int ts = tid & 127; // thread id within stream

  const int bid = blockIdx.x;
  const int vb = (bid & 7) * 64 + (bid >> 3);  // XCD swizzle: 4 bh per XCD
  const int tbp = vb & 15, bh = vb >> 4;
  const int tq0 = tbp * 128 + u * 64;

  const u16* qb = wsQ + (size_t)bh * (SEQ * 64);
  const u16* kb = wsK + (size_t)bh * (SEQ * 64);
  const u16* vstream = wsV + (size_t)bh * 131072 + lane * 8;

  char* Kbuf = smem + sh * 8192;

  // Q fragments: qf[cb][ks] = Q[t=tq0+cb*32+tl][c=16ks+8hi .. +7]
  short8 qf[2][4];
#pragma unroll
  for (int cb = 0; cb < 2; ++cb) {
    const u16* qrow = qb + (size_t)(tq0 + cb * 32 + tl) * 64 + 8 * hi;
#pragma unroll
    for (int ks = 0; ks < 4; ++ks) qf[cb][ks] = *(const short8*)(qrow + 16 * ks);
  }

  f32x16 acc[4];  // [cb*2+ct]
#pragma unroll
  for (int a = 0; a < 4; ++a)
#pragma unroll
    for (int r = 0; r < 16; ++r) acc[a][r] = 0.0f;
  float la0[2] = {0, 0};
  float la1[2] = {0, 0};

  uint4 kg[2];
  const int krow_s = ts >> 2, kg2 = ts & 3;  // staging: row krow_s, 32B at col kg2*16

#define STAGE_LOAD(S)                                                        \
  do {                                                                       \
    const u16* _kp = kb + (size_t)((S) + krow_s) * 64 + kg2 * 16;            \
    kg[0] = *(const uint4*)(_kp);                                            \
    kg[1] = *(const uint4*)(_kp + 8);                                        \
  } while (0)

#define STAGE_WRITE(PBUF)                                                    \
  do {                                                                       \
    char* _kd = Kbuf + (PBUF) * 4096 + krow_s * 128;                         \
    *(uint4*)(_kd + (((2 * kg2) ^ (krow_s & 7)) << 4)) = kg[0];              \
    *(uint4*)(_kd + (((2 * kg2 + 1) ^ (krow_s & 7)) << 4)) = kg[1];          \
  } while (0)

#define PACK_P(PV16, PF0, PF1)                                                        \
  do {                                                                                \
    u32 _pk[8];                                                                       \
    _Pragma("unroll")                                                                 \
    for (int _q = 0; _q < 8; ++_q) {                                                  \
      const float _lo = PV16[2 * _q], _hi = PV16[2 * _q + 1];                         \
      asm("v_cvt_pk_bf16_f32 %0, %1, %2" : "=v"(_pk[_q]) : "v"(_lo), "v"(_hi));       \
    }                                                                                 \
    asm("v_permlane32_swap_b32 %0, %1" : "+v"(_pk[0]), "+v"(_pk[2]));                 \
    asm("v_permlane32_swap_b32 %0, %1" : "+v"(_pk[1]), "+v"(_pk[3]));                 \
    asm("v_permlane32_swap_b32 %0, %1" : "+v"(_pk[4]), "+v"(_pk[6]));                 \
    asm("v_permlane32_swap_b32 %0, %1" : "+v"(_pk[5]), "+v"(_pk[7]));                 \
    union { u32 u[4]; short8 v; } _f0, _f1;                                           \
    _f0.u[0] = _pk[0]; _f0.u[1] = _pk[1]; _f0.u[2] = _pk[2]; _f0.u[3] = _pk[3];       \
    _f1.u[0] = _pk[4]; _f1.u[1] = _pk[5]; _f1.u[2] = _pk[6]; _f1.u[3] = _pk[7];       \
    PF0 = _f0.v; PF1 = _f1.v;                                                         \
  } while (0)

  // prologue: stage tile 0 into buf 0
  STAGE_LOAD(sh * 1024);
  STAGE_WRITE(0);
  __syncthreads();

  for (int i = 0; i < 32; ++i) {
    if (i < 31) STAGE_LOAD(sh * 1024 + (i + 1) * 32);  // T14: load-early

    const char* Ks = Kbuf + (i & 1) * 4096;

    // kf for this 32-s tile
    short8 kf[4];
#pragma unroll
    for (int ks = 0; ks < 4; ++ks)
      kf[ks] = *(const short8*)(Ks + tl * 128 + (((2 * ks + hi) ^ (tl & 7)) << 4));

    f32x16 s0 = {0, 0, 0, 0, 0, 0, 0, 0, 0, 0, 0, 0, 0, 0, 0, 0};
    f32x16 s1 = s0;
    __builtin_amdgcn_s_setprio(1);
#pragma unroll
    for (int ks = 0; ks < 4; ++ks) {
      s0 = __builtin_amdgcn_mfma_f32_32x32x16_bf16(kf[ks], qf[0][ks], s0, 0, 0, 0);
      s1 = __builtin_amdgcn_mfma_f32_32x32x16_bf16(kf[ks], qf[1][ks], s1, 0, 0, 0);
    }
    __builtin_amdgcn_s_setprio(0);

    // mid-iter STAGE_WRITE: kg arrived long ago; softmax+PV below covers ds_write latency
    if (i < 31) STAGE_WRITE((i + 1) & 1);

    // V fragments direct from fragment-linear V' (coalesced)
    const u16* vp = vstream + (size_t)(sh * 32 + i) * 2048;
    const short8 vf0 = *(const short8*)(vp);
    const short8 vf1 = *(const short8*)(vp + 512);
    const short8 vf2 = *(const short8*)(vp + 1024);
    const short8 vf3 = *(const short8*)(vp + 1536);

#pragma unroll
    for (int r = 0; r < 16; ++r) s0[r] = exp2fast(s0[r]);
#pragma unroll
    for (int r = 0; r < 16; ++r) s1[r] = exp2fast(s1[r]);
#pragma unroll
    for (int j = 0; j < 2; ++j) {
      la0[j] += ((s0[8 * j] + s0[8 * j + 1]) + (s0[8 * j + 2] + s0[8 * j + 3])) +
                ((s0[8 * j + 4] + s0[8 * j + 5]) + (s0[8 * j + 6] + s0[8 * j + 7]));
      la1[j] += ((s1[8 * j] + s1[8 * j + 1]) + (s1[8 * j + 2] + s1[8 * j + 3])) +
                ((s1[8 * j + 4] + s1[8 * j + 5]) + (s1[8 * j + 6] + s1[8 * j + 7]));
    }

    short8 pf00, pf01, pf10, pf11;
    PACK_P(s0, pf00, pf01);
    PACK_P(s1, pf10, pf11);

    __builtin_amdgcn_s_setprio(1);
    acc[0] = __builtin_amdgcn_mfma_f32_32x32x16_bf16(vf0, pf00, acc[0], 0, 0, 0);
    acc[0] = __builtin_amdgcn_mfma_f32_32x32x16_bf16(vf1, pf01, acc[0], 0, 0, 0);
    acc[1] = __builtin_amdgcn_mfma_f32_32x32x16_bf16(vf2, pf00, acc[1], 0, 0, 0);
    acc[1] = __builtin_amdgcn_mfma_f32_32x32x16_bf16(vf3, pf01, acc[1], 0, 0, 0);
    acc[2] = __builtin_amdgcn_mfma_f32_32x32x16_bf16(vf0, pf10, acc[2], 0, 0, 0);
    acc[2] = __builtin_amdgcn_mfma_f32_32x32x16_bf16(vf1, pf11, acc[2], 0, 0, 0);
    acc[3] = __builtin_amdgcn_mfma_f32_32x32x16_bf16(vf2, pf10, acc[3], 0, 0, 0);
    acc[3] = __builtin_amdgcn_mfma_f32_32x32x16_bf16(vf3, pf11, acc[3], 0, 0, 0);
    __builtin_amdgcn_s_setprio(0);

    __syncthreads();
  }

  // ---- epilogue: reduce l, 2-stream merge (fixed m => plain sums), store ----
  float l0 = la0[0] + la0[1];
  float l1 = la1[0] + la1[1];
  l0 += __shfl_xor(l0, 32, 64);
  l1 += __shfl_xor(l1, 32, 64);

  float* Xa = (float*)(smem + u * 16384);
  if (sh == 1) {
#pragma unroll
    for (int a = 0; a < 4; ++a)
#pragma unroll
      for (int r = 0; r < 16; ++r) Xa[(a * 16 + r) * 64 + lane] = acc[a][r];
    Xl[u][0][tl] = l0;
    Xl[u][1][tl] = l1;
  }
  __syncthreads();
  if (sh == 0) {
    float* ob = out + (size_t)bh * 64 * SEQ;
    const float inv0 = 1.0f / (l0 + Xl[u][0][tl]);
    const float inv1 = 1.0f / (l1 + Xl[u][1][tl]);
#pragma unroll
    for (int r = 0; r < 16; ++r) {
      const int c0 = (r & 3) + 8 * (r >> 2) + 4 * hi;
      const int ta = tq0 + tl, tb2 = tq0 + 32 + tl;
      ob[(size_t)c0 * SEQ + ta] = (acc[0][r] + Xa[(0 * 16 + r) * 64 + lane]) * inv0;
      ob[(size_t)(c0 + 32) * SEQ + ta] = (acc[1][r] + Xa[(1 * 16 + r) * 64 + lane]) * inv0;
      ob[(size_t)c0 * SEQ + tb2] = (acc[2][r] + Xa[(2 * 16 + r) * 64 + lane]) * inv1;
      ob[(size_t)(c0 + 32) * SEQ + tb2] = (acc[3][r] + Xa[(3 * 16 + r) * 64 + lane]) * inv1;
    }
  }
}

extern "C" void kernel_launch(void* const* d_in, const int* in_sizes, int n_in,
                              void* d_out, int out_size, void* d_ws, size_t ws_size,
                              hipStream_t stream) {
  const float* qkv = (const float*)d_in[0];
  float* out = (float*)d_out;
  u16* wsQ = (u16*)d_ws;
  u16* wsK = wsQ + (size_t)32 * SEQ * 64;
  u16* wsV = wsK + (size_t)32 * SEQ * 64;

  prep_all<<<dim3(32, 32, 3), 256, 0, stream>>>(qkv, wsQ, wsK, wsV);
  attn_kernel<<<512, 256, 0, stream>>>(wsQ, wsK, wsV, out);
}

// Round 18
// 57.074 us; speedup vs baseline: 1.1408x; 1.1408x over previous
//
#include <hip/hip_runtime.h>
#include <hip/hip_bf16.h>

typedef unsigned short u16;
typedef unsigned int u32;
typedef __attribute__((ext_vector_type(8))) short short8;
typedef __attribute__((ext_vector_type(16))) float f32x16;

#define SEQ 2048

__device__ __forceinline__ u16 f2bf(float f) {
  union { __hip_bfloat16 h; u16 u; } c;
  c.h = __float2bfloat16(f);
  return c.u;
}

__device__ __forceinline__ float exp2fast(float x) {
  return __builtin_amdgcn_exp2f(x);  // v_exp_f32 (base-2)
}

// ---------------- fused prep (identical to R16) ----------------
__global__ __launch_bounds__(256) void prep_all(const float* __restrict__ qkv,
                                                u16* __restrict__ wsQ,
                                                u16* __restrict__ wsK,
                                                u16* __restrict__ wsV) {
  const int tid = threadIdx.x;
  const int bh = blockIdx.y;
  const int b = bh >> 3, h = bh & 7;
  const int z = blockIdx.z;

  if (z == 2) {
#pragma unroll
    for (int rep = 0; rep < 2; ++rep) {
      const int il = rep * 256 + tid;
      const int j = 2 * blockIdx.x + (il >> 8);
      const int slot = il & 255;
      const int lane = slot & 63;
      const int ctks = slot >> 6;
      const int ct = ctks >> 1, ks2 = ctks & 1;
      const int hi = lane >> 5, tl = lane & 31;
      const int cc = ct * 32 + tl;
      const int s = j * 32 + ks2 * 16 + hi * 8;
      const float* src = qkv + ((size_t)b * 1536 + 1024 + (size_t)h * 64 + cc) * SEQ + s;
      const float4 v0 = *(const float4*)(src);
      const float4 v1 = *(const float4*)(src + 4);
      union { u16 us[8]; uint4 q; } pk;
      pk.us[0] = f2bf(v0.x); pk.us[1] = f2bf(v0.y); pk.us[2] = f2bf(v0.z); pk.us[3] = f2bf(v0.w);
      pk.us[4] = f2bf(v1.x); pk.us[5] = f2bf(v1.y); pk.us[6] = f2bf(v1.z); pk.us[7] = f2bf(v1.w);
      *(uint4*)(wsV + ((size_t)bh * 16384 + (size_t)j * 256 + slot) * 8) = pk.q;
    }
    return;
  }

  __shared__ float tile[64 * 67];
  const int t0 = blockIdx.x * 64;
  const int isK = z;
  const float scale = 0.42466090014692505f;  // 64^-0.25 * sqrt(log2 e)
  const size_t inbase = ((size_t)b * 1536 + (size_t)isK * 512 + (size_t)h * 64) * SEQ;

  const int c = tid >> 2, tq = tid & 3;
#pragma unroll
  for (int u = 0; u < 4; ++u) {
    const int t = tq * 16 + u * 4;
    const float4 v = *(const float4*)(qkv + inbase + (size_t)c * SEQ + t0 + t);
    tile[c * 67 + t + 0] = v.x * scale;
    tile[c * 67 + t + 1] = v.y * scale;
    tile[c * 67 + t + 2] = v.z * scale;
    tile[c * 67 + t + 3] = v.w * scale;
  }
  __syncthreads();
  const int tt = tid >> 2, cq = tid & 3, c0 = cq * 16;
  u16* dst = (isK ? wsK : wsQ) + ((size_t)bh * SEQ + t0 + tt) * 64 + c0;
  union { u16 us[8]; uint4 v; } p0, p1;
#pragma unroll
  for (int i = 0; i < 8; ++i) p0.us[i] = f2bf(tile[(c0 + i) * 67 + tt]);
#pragma unroll
  for (int i = 0; i < 8; ++i) p1.us[i] = f2bf(tile[(c0 + 8 + i) * 67 + tt]);
  *(uint4*)(dst) = p0.v;
  *(uint4*)(dst + 8) = p1.v;
}

// ---------------- fused flash attention (R16 + T15 2-deep score pipeline) ----------------
// 512 thr = 8 waves = 2 s-half streams x 4 t-units. Wave: QBLK=64 t, 1024 s.
// K staged in LDS (8KB/stream/iter, XOR-swizzled, dbuf, load-early/write-mid, 1 barrier/iter).
// V DIRECT from fragment-linear V'. Fixed-m exp2 softmax.
// T15: QK(j+1) MFMAs issue BEFORE softmax/PV(j) -> matrix pipe fills under VALU work.
__global__ __launch_bounds__(512) void attn_kernel(const u16* __restrict__ wsQ,
                                                   const u16* __restrict__ wsK,
                                                   const u16* __restrict__ wsV,
                                                   float* __restrict__ out) {
  __shared__ __align__(16) char smem[65536];
  __shared__ float Xl[4][2][32];  // [unit][cb][tl]

  const int tid = threadIdx.x;
  const int w = tid >> 6;
  const int lane = tid & 63;
  const int tl = lane & 31;
  const int hi = lane >> 5;
  const int sh = w >> 2;    // s-half stream
  const int u = w & 3;      // t-unit within block
  const int ts = tid & 255; // thread id within stream

  const int bid = blockIdx.x;
  const int vb = (bid & 7) * 32 + (bid >> 3);  // XCD swizzle: 4 bh per XCD
  const int tblk = vb & 7, bh = vb >> 3;
  const int tq0 = tblk * 256 + u * 64;

  const u16* qb = wsQ + (size_t)bh * (SEQ * 64);
  const u16* kb = wsK + (size_t)bh * (SEQ * 64);
  const u16* vstream = wsV + (size_t)bh * 131072 + lane * 8;

  char* Kbuf = smem + sh * 16384;

  // Q fragments: qf[cb][ks] = Q[t=tq0+cb*32+tl][c=16ks+8hi .. +7]
  short8 qf[2][4];
#pragma unroll
  for (int cb = 0; cb < 2; ++cb) {
    const u16* qrow = qb + (size_t)(tq0 + cb * 32 + tl) * 64 + 8 * hi;
#pragma unroll
    for (int ks = 0; ks < 4; ++ks) qf[cb][ks] = *(const short8*)(qrow + 16 * ks);
  }

  f32x16 acc[4];  // [cb*2+ct]
#pragma unroll
  for (int a = 0; a < 4; ++a)
#pragma unroll
    for (int r = 0; r < 16; ++r) acc[a][r] = 0.0f;
  float la0[2] = {0, 0};
  float la1[2] = {0, 0};

  uint4 kg[2];

#define STAGE_LOAD(S)                                                       \
  do {                                                                      \
    _Pragma("unroll")                                                       \
    for (int _it = 0; _it < 2; ++_it) {                                     \
      const int _idx = _it * 256 + ts;                                      \
      const int _row = _idx >> 3, _g = _idx & 7;                            \
      kg[_it] = *(const uint4*)(kb + (size_t)((S) + _row) * 64 + _g * 8);   \
    }                                                                       \
  } while (0)

#define STAGE_WRITE(PBUF)                                                   \
  do {                                                                      \
    char* _kd = Kbuf + (PBUF) * 8192;                                       \
    _Pragma("unroll")                                                       \
    for (int _it = 0; _it < 2; ++_it) {                                     \
      const int _idx = _it * 256 + ts;                                      \
      const int _row = _idx >> 3, _g = _idx & 7;                            \
      *(uint4*)(_kd + _row * 128 + ((_g ^ (_row & 7)) << 4)) = kg[_it];     \
    }                                                                       \
  } while (0)

#define PACK_P(PV16, PF0, PF1)                                                        \
  do {                                                                                \
    u32 _pk[8];                                                                       \
    _Pragma("unroll")                                                                 \
    for (int _q = 0; _q < 8; ++_q) {                                                  \
      const float _lo = PV16[2 * _q], _hi = PV16[2 * _q + 1];                         \
      asm("v_cvt_pk_bf16_f32 %0, %1, %2" : "=v"(_pk[_q]) : "v"(_lo), "v"(_hi));       \
    }                                                                                 \
    asm("v_permlane32_swap_b32 %0, %1" : "+v"(_pk[0]), "+v"(_pk[2]));                 \
    asm("v_permlane32_swap_b32 %0, %1" : "+v"(_pk[1]), "+v"(_pk[3]));                 \
    asm("v_permlane32_swap_b32 %0, %1" : "+v"(_pk[4]), "+v"(_pk[6]));                 \
    asm("v_permlane32_swap_b32 %0, %1" : "+v"(_pk[5]), "+v"(_pk[7]));                 \
    union { u32 u[4]; short8 v; } _f0, _f1;                                           \
    _f0.u[0] = _pk[0]; _f0.u[1] = _pk[1]; _f0.u[2] = _pk[2]; _f0.u[3] = _pk[3];       \
    _f1.u[0] = _pk[4]; _f1.u[1] = _pk[5]; _f1.u[2] = _pk[6]; _f1.u[3] = _pk[7];       \
    PF0 = _f0.v; PF1 = _f1.v;                                                         \
  } while (0)

  // QK for one 32-s subtile -> named score regs (no finish)
#define QKSTEP(SS, BUF, S0, S1)                                                         \
  do {                                                                                  \
    const char* _Ks = Kbuf + (BUF) * 8192;                                              \
    const int _krow = (SS) * 32 + tl;                                                   \
    short8 _kf[4];                                                                      \
    _Pragma("unroll")                                                                   \
    for (int _ks = 0; _ks < 4; ++_ks)                                                   \
      _kf[_ks] = *(const short8*)(_Ks + _krow * 128 + (((2 * _ks + hi) ^ (_krow & 7)) << 4)); \
    _Pragma("unroll")                                                                   \
    for (int _r = 0; _r < 16; ++_r) { S0[_r] = 0.0f; S1[_r] = 0.0f; }                   \
    __builtin_amdgcn_s_setprio(1);                                                      \
    _Pragma("unroll")                                                                   \
    for (int _ks = 0; _ks < 4; ++_ks) {                                                 \
      S0 = __builtin_amdgcn_mfma_f32_32x32x16_bf16(_kf[_ks], qf[0][_ks], S0, 0, 0, 0);  \
      S1 = __builtin_amdgcn_mfma_f32_32x32x16_bf16(_kf[_ks], qf[1][_ks], S1, 0, 0, 0);  \
    }                                                                                   \
    __builtin_amdgcn_s_setprio(0);                                                      \
  } while (0)

  // softmax finish + PV for one subtile (consumes score regs)
#define FINISH(S0, S1, JJ)                                                              \
  do {                                                                                  \
    const u16* _vp = vstream + (size_t)(JJ) * 2048;                                     \
    const short8 _vf0 = *(const short8*)(_vp);                                          \
    const short8 _vf1 = *(const short8*)(_vp + 512);                                    \
    const short8 _vf2 = *(const short8*)(_vp + 1024);                                   \
    const short8 _vf3 = *(const short8*)(_vp + 1536);                                   \
    _Pragma("unroll")                                                                   \
    for (int _r = 0; _r < 16; ++_r) S0[_r] = exp2fast(S0[_r]);                          \
    _Pragma("unroll")                                                                   \
    for (int _r = 0; _r < 16; ++_r) S1[_r] = exp2fast(S1[_r]);                          \
    _Pragma("unroll")                                                                   \
    for (int _j = 0; _j < 2; ++_j) {                                                    \
      la0[_j] += ((S0[8 * _j] + S0[8 * _j + 1]) + (S0[8 * _j + 2] + S0[8 * _j + 3])) + \
                 ((S0[8 * _j + 4] + S0[8 * _j + 5]) + (S0[8 * _j + 6] + S0[8 * _j + 7])); \
      la1[_j] += ((S1[8 * _j] + S1[8 * _j + 1]) + (S1[8 * _j + 2] + S1[8 * _j + 3])) + \
                 ((S1[8 * _j + 4] + S1[8 * _j + 5]) + (S1[8 * _j + 6] + S1[8 * _j + 7])); \
    }                                                                                   \
    short8 _pf00, _pf01, _pf10, _pf11;                                                  \
    PACK_P(S0, _pf00, _pf01);                                                           \
    PACK_P(S1, _pf10, _pf11);                                                           \
    __builtin_amdgcn_s_setprio(1);                                                      \
    acc[0] = __builtin_amdgcn_mfma_f32_32x32x16_bf16(_vf0, _pf00, acc[0], 0, 0, 0);     \
    acc[0] = __builtin_amdgcn_mfma_f32_32x32x16_bf16(_vf1, _pf01, acc[0], 0, 0, 0);     \
    acc[1] = __builtin_amdgcn_mfma_f32_32x32x16_bf16(_vf2, _pf00, acc[1], 0, 0, 0);     \
    acc[1] = __builtin_amdgcn_mfma_f32_32x32x16_bf16(_vf3, _pf01, acc[1], 0, 0, 0);     \
    acc[2] = __builtin_amdgcn_mfma_f32_32x32x16_bf16(_vf0, _pf10, acc[2], 0, 0, 0);     \
    acc[2] = __builtin_amdgcn_mfma_f32_32x32x16_bf16(_vf1, _pf11, acc[2], 0, 0, 0);     \
    acc[3] = __builtin_amdgcn_mfma_f32_32x32x16_bf16(_vf2, _pf10, acc[3], 0, 0, 0);     \
    acc[3] = __builtin_amdgcn_mfma_f32_32x32x16_bf16(_vf3, _pf11, acc[3], 0, 0, 0);     \
    __builtin_amdgcn_s_setprio(0);                                                      \
  } while (0)

  // prologue: stage tile 0, then QK(subtile 0) into sA
  STAGE_LOAD(sh * 1024);
  STAGE_WRITE(0);
  __syncthreads();

  f32x16 sA0, sA1, sB0, sB1;
  QKSTEP(0, 0, sA0, sA1);

  for (int i = 0; i < 16; ++i) {
    if (i < 15) STAGE_LOAD(sh * 1024 + (i + 1) * 64);  // T14: load-early
    const int jbase = sh * 32 + i * 2;

    // T15: issue next subtile's QK before finishing the previous one
    QKSTEP(1, i & 1, sB0, sB1);
    FINISH(sA0, sA1, jbase);          // VALU work overlaps sB's MFMAs

    if (i < 15) STAGE_WRITE((i + 1) & 1);  // write-mid, covered by compute
    __syncthreads();                        // buffer (i+1)&1 ready

    if (i < 15) QKSTEP(0, (i + 1) & 1, sA0, sA1);
    FINISH(sB0, sB1, jbase + 1);      // overlaps sA's MFMAs
  }

  // ---- epilogue: reduce l, 2-stream merge (fixed m => plain sums), store ----
  __syncthreads();  // all K-buffer reads done before smem reuse
  float l0 = la0[0] + la0[1];
  float l1 = la1[0] + la1[1];
  l0 += __shfl_xor(l0, 32, 64);
  l1 += __shfl_xor(l1, 32, 64);

  float* Xa = (float*)smem + u * 4096;
  if (sh == 1) {
#pragma unroll
    for (int a = 0; a < 4; ++a)
#pragma unroll
      for (int r = 0; r < 16; ++r) Xa[(a * 16 + r) * 64 + lane] = acc[a][r];
    Xl[u][0][tl] = l0;
    Xl[u][1][tl] = l1;
  }
  __syncthreads();
  if (sh == 0) {
    float* ob = out + (size_t)bh * 64 * SEQ;
    const float inv0 = 1.0f / (l0 + Xl[u][0][tl]);
    const float inv1 = 1.0f / (l1 + Xl[u][1][tl]);
#pragma unroll
    for (int r = 0; r < 16; ++r) {
      const int c0 = (r & 3) + 8 * (r >> 2) + 4 * hi;
      const int ta = tq0 + tl, tb2 = tq0 + 32 + tl;
      ob[(size_t)c0 * SEQ + ta] = (acc[0][r] + Xa[(0 * 16 + r) * 64 + lane]) * inv0;
      ob[(size_t)(c0 + 32) * SEQ + ta] = (acc[1][r] + Xa[(1 * 16 + r) * 64 + lane]) * inv0;
      ob[(size_t)c0 * SEQ + tb2] = (acc[2][r] + Xa[(2 * 16 + r) * 64 + lane]) * inv1;
      ob[(size_t)(c0 + 32) * SEQ + tb2] = (acc[3][r] + Xa[(3 * 16 + r) * 64 + lane]) * inv1;
    }
  }
}

extern "C" void kernel_launch(void* const* d_in, const int* in_sizes, int n_in,
                              void* d_out, int out_size, void* d_ws, size_t ws_size,
                              hipStream_t stream) {
  const float* qkv = (const float*)d_in[0];
  float* out = (float*)d_out;
  u16* wsQ = (u16*)d_ws;
  u16* wsK = wsQ + (size_t)32 * SEQ * 64;
  u16* wsV = wsK + (size_t)32 * SEQ * 64;

  prep_all<<<dim3(32, 32, 3), 256, 0, stream>>>(qkv, wsQ, wsK, wsV);
  attn_kernel<<<256, 512, 0, stream>>>(wsQ, wsK, wsV, out);
}

// Round 19
// 53.244 us; speedup vs baseline: 1.2228x; 1.0719x over previous
//
#include <hip/hip_runtime.h>
#include <hip/hip_bf16.h>

typedef unsigned short u16;
typedef unsigned int u32;
typedef __attribute__((ext_vector_type(8))) short short8;
typedef __attribute__((ext_vector_type(16))) float f32x16;

#define SEQ 2048

__device__ __forceinline__ u16 f2bf(float f) {
  union { __hip_bfloat16 h; u16 u; } c;
  c.h = __float2bfloat16(f);
  return c.u;
}

__device__ __forceinline__ float exp2fast(float x) {
  return __builtin_amdgcn_exp2f(x);  // v_exp_f32 (base-2)
}

// ---------------- fused prep (K + V only; Q is read directly by attn) ----------------
// z=0: K -> ws [bh][seq][64] row-major (scaled).
// z=1: V -> fragment-linear V'[bh][sb32][ct*2+ks2][lane][8] (2 sb32-tiles per block).
// scale = 64^-0.25 * sqrt(log2 e)  (exp2-domain softmax)
__global__ __launch_bounds__(256) void prep_all(const float* __restrict__ qkv,
                                                u16* __restrict__ wsK,
                                                u16* __restrict__ wsV) {
  const int tid = threadIdx.x;
  const int bh = blockIdx.y;
  const int b = bh >> 3, h = bh & 7;

  if (blockIdx.z == 1) {
    // V-prep: block x covers tiles j = 2x, 2x+1
#pragma unroll
    for (int rep = 0; rep < 2; ++rep) {
      const int il = rep * 256 + tid;           // 0..511
      const int j = 2 * blockIdx.x + (il >> 8); // sb32 tile
      const int slot = il & 255;
      const int lane = slot & 63;
      const int ctks = slot >> 6;
      const int ct = ctks >> 1, ks2 = ctks & 1;
      const int hi = lane >> 5, tl = lane & 31;
      const int cc = ct * 32 + tl;
      const int s = j * 32 + ks2 * 16 + hi * 8;
      const float* src = qkv + ((size_t)b * 1536 + 1024 + (size_t)h * 64 + cc) * SEQ + s;
      const float4 v0 = *(const float4*)(src);
      const float4 v1 = *(const float4*)(src + 4);
      union { u16 us[8]; uint4 q; } pk;
      pk.us[0] = f2bf(v0.x); pk.us[1] = f2bf(v0.y); pk.us[2] = f2bf(v0.z); pk.us[3] = f2bf(v0.w);
      pk.us[4] = f2bf(v1.x); pk.us[5] = f2bf(v1.y); pk.us[6] = f2bf(v1.z); pk.us[7] = f2bf(v1.w);
      *(uint4*)(wsV + ((size_t)bh * 16384 + (size_t)j * 256 + slot) * 8) = pk.q;
    }
    return;
  }

  // K-prep: transpose+scale -> [bh][s][64]
  __shared__ float tile[64 * 67];
  const int t0 = blockIdx.x * 64;
  const float scale = 0.42466090014692505f;  // 64^-0.25 * sqrt(log2 e)
  const size_t inbase = ((size_t)b * 1536 + 512 + (size_t)h * 64) * SEQ;

  const int c = tid >> 2, tq = tid & 3;
#pragma unroll
  for (int u = 0; u < 4; ++u) {
    const int t = tq * 16 + u * 4;
    const float4 v = *(const float4*)(qkv + inbase + (size_t)c * SEQ + t0 + t);
    tile[c * 67 + t + 0] = v.x * scale;
    tile[c * 67 + t + 1] = v.y * scale;
    tile[c * 67 + t + 2] = v.z * scale;
    tile[c * 67 + t + 3] = v.w * scale;
  }
  __syncthreads();
  const int tt = tid >> 2, cq = tid & 3, c0 = cq * 16;
  u16* dst = wsK + ((size_t)bh * SEQ + t0 + tt) * 64 + c0;
  union { u16 us[8]; uint4 v; } p0, p1;
#pragma unroll
  for (int i = 0; i < 8; ++i) p0.us[i] = f2bf(tile[(c0 + i) * 67 + tt]);
#pragma unroll
  for (int i = 0; i < 8; ++i) p1.us[i] = f2bf(tile[(c0 + 8 + i) * 67 + tt]);
  *(uint4*)(dst) = p0.v;
  *(uint4*)(dst + 8) = p1.v;
}

// ---------------- fused flash attention (R16 structure; Q direct from qkv) ----------------
// 512 thr = 8 waves = 2 s-half streams x 4 t-units. Wave: QBLK=64 t, 1024 s.
// K staged in LDS (8KB/stream/iter, XOR-swizzled, dbuf, load-early/write-mid, 1 barrier/iter).
// V DIRECT from fragment-linear V'. Fixed-m softmax (p = exp2(S)); final /l = exact softmax.
// grid 256 (XCD-swizzled: 4 bh per XCD).
__global__ __launch_bounds__(512) void attn_kernel(const float* __restrict__ qkv,
                                                   const u16* __restrict__ wsK,
                                                   const u16* __restrict__ wsV,
                                                   float* __restrict__ out) {
  // main loop: stream sh owns [sh*16384, +16KB) = 2 x 8KB K double-buffer.
  // epilogue: reused as 4 x 16KB float partial slots.
  __shared__ __align__(16) char smem[65536];
  __shared__ float Xl[4][2][32];  // [unit][cb][tl]

  const int tid = threadIdx.x;
  const int w = tid >> 6;
  const int lane = tid & 63;
  const int tl = lane & 31;
  const int hi = lane >> 5;
  const int sh = w >> 2;    // s-half stream
  const int u = w & 3;      // t-unit within block
  const int ts = tid & 255; // thread id within stream

  const int bid = blockIdx.x;
  const int vb = (bid & 7) * 32 + (bid >> 3);  // XCD swizzle: 4 bh per XCD
  const int tblk = vb & 7, bh = vb >> 3;
  const int tq0 = tblk * 256 + u * 64;
  const int b0 = bh >> 3, h0 = bh & 7;

  const u16* kb = wsK + (size_t)bh * (SEQ * 64);
  const u16* vstream = wsV + (size_t)bh * 131072 + lane * 8;

  char* Kbuf = smem + sh * 16384;

  // Q fragments DIRECT from qkv (one-time): qf[cb][ks] = Q[t=tq0+cb*32+tl][c=16ks+8hi+e]*scale
  const float qscale = 0.42466090014692505f;
  short8 qf[2][4];
  {
    const float* qsrc = qkv + ((size_t)b0 * 1536 + (size_t)h0 * 64) * SEQ;
#pragma unroll
    for (int cb = 0; cb < 2; ++cb) {
      const int t = tq0 + cb * 32 + tl;
#pragma unroll
      for (int ks = 0; ks < 4; ++ks) {
        union { u16 us[8]; short8 v; } qq;
#pragma unroll
        for (int e = 0; e < 8; ++e)
          qq.us[e] = f2bf(qsrc[(size_t)(16 * ks + 8 * hi + e) * SEQ + t] * qscale);
        qf[cb][ks] = qq.v;
      }
    }
  }

  f32x16 acc[4];  // [cb*2+ct]
#pragma unroll
  for (int a = 0; a < 4; ++a)
#pragma unroll
    for (int r = 0; r < 16; ++r) acc[a][r] = 0.0f;
  float la0[2] = {0, 0};
  float la1[2] = {0, 0};

  uint4 kg[2];

#define STAGE_LOAD(S)                                                       \
  do {                                                                      \
    _Pragma("unroll")                                                       \
    for (int _it = 0; _it < 2; ++_it) {                                     \
      const int _idx = _it * 256 + ts;                                      \
      const int _row = _idx >> 3, _g = _idx & 7;                            \
      kg[_it] = *(const uint4*)(kb + (size_t)((S) + _row) * 64 + _g * 8);   \
    }                                                                       \
  } while (0)

#define STAGE_WRITE(PBUF)                                                   \
  do {                                                                      \
    char* _kd = Kbuf + (PBUF) * 8192;                                       \
    _Pragma("unroll")                                                       \
    for (int _it = 0; _it < 2; ++_it) {                                     \
      const int _idx = _it * 256 + ts;                                      \
      const int _row = _idx >> 3, _g = _idx & 7;                            \
      *(uint4*)(_kd + _row * 128 + ((_g ^ (_row & 7)) << 4)) = kg[_it];     \
    }                                                                       \
  } while (0)

#define PACK_P(PV16, PF0, PF1)                                                        \
  do {                                                                                \
    u32 _pk[8];                                                                       \
    _Pragma("unroll")                                                                 \
    for (int _q = 0; _q < 8; ++_q) {                                                  \
      const float _lo = PV16[2 * _q], _hi = PV16[2 * _q + 1];                         \
      asm("v_cvt_pk_bf16_f32 %0, %1, %2" : "=v"(_pk[_q]) : "v"(_lo), "v"(_hi));       \
    }                                                                                 \
    asm("v_permlane32_swap_b32 %0, %1" : "+v"(_pk[0]), "+v"(_pk[2]));                 \
    asm("v_permlane32_swap_b32 %0, %1" : "+v"(_pk[1]), "+v"(_pk[3]));                 \
    asm("v_permlane32_swap_b32 %0, %1" : "+v"(_pk[4]), "+v"(_pk[6]));                 \
    asm("v_permlane32_swap_b32 %0, %1" : "+v"(_pk[5]), "+v"(_pk[7]));                 \
    union { u32 u[4]; short8 v; } _f0, _f1;                                           \
    _f0.u[0] = _pk[0]; _f0.u[1] = _pk[1]; _f0.u[2] = _pk[2]; _f0.u[3] = _pk[3];       \
    _f1.u[0] = _pk[4]; _f1.u[1] = _pk[5]; _f1.u[2] = _pk[6]; _f1.u[3] = _pk[7];       \
    PF0 = _f0.v; PF1 = _f1.v;                                                         \
  } while (0)

  // one 32-s subtile: QK -> exp2 -> l -> pack -> PV
#define SUBTILE(SS, JJ)                                                               \
  do {                                                                                \
    const int krow = (SS) * 32 + tl;                                                  \
    short8 kf[4];                                                                     \
    _Pragma("unroll")                                                                 \
    for (int ks = 0; ks < 4; ++ks)                                                    \
      kf[ks] = *(const short8*)(Ks + krow * 128 + (((2 * ks + hi) ^ (krow & 7)) << 4)); \
    f32x16 s0 = {0, 0, 0, 0, 0, 0, 0, 0, 0, 0, 0, 0, 0, 0, 0, 0};                    \
    f32x16 s1 = s0;                                                                   \
    __builtin_amdgcn_s_setprio(1);                                                    \
    _Pragma("unroll")                                                                 \
    for (int ks = 0; ks < 4; ++ks) {                                                  \
      s0 = __builtin_amdgcn_mfma_f32_32x32x16_bf16(kf[ks], qf[0][ks], s0, 0, 0, 0);   \
      s1 = __builtin_amdgcn_mfma_f32_32x32x16_bf16(kf[ks], qf[1][ks], s1, 0, 0, 0);   \
    }                                                                                 \
    __builtin_amdgcn_s_setprio(0);                                                    \
    const u16* vp = vstream + (size_t)(JJ) * 2048;                                    \
    const short8 vf0 = *(const short8*)(vp);                                          \
    const short8 vf1 = *(const short8*)(vp + 512);                                    \
    const short8 vf2 = *(const short8*)(vp + 1024);                                   \
    const short8 vf3 = *(const short8*)(vp + 1536);                                   \
    _Pragma("unroll")                                                                 \
    for (int r = 0; r < 16; ++r) s0[r] = exp2fast(s0[r]);                             \
    _Pragma("unroll")                                                                 \
    for (int r = 0; r < 16; ++r) s1[r] = exp2fast(s1[r]);                             \
    _Pragma("unroll")                                                                 \
    for (int j = 0; j < 2; ++j) {                                                     \
      la0[j] += ((s0[8 * j] + s0[8 * j + 1]) + (s0[8 * j + 2] + s0[8 * j + 3])) +     \
                ((s0[8 * j + 4] + s0[8 * j + 5]) + (s0[8 * j + 6] + s0[8 * j + 7]));  \
      la1[j] += ((s1[8 * j] + s1[8 * j + 1]) + (s1[8 * j + 2] + s1[8 * j + 3])) +     \
                ((s1[8 * j + 4] + s1[8 * j + 5]) + (s1[8 * j + 6] + s1[8 * j + 7]));  \
    }                                                                                 \
    short8 pf00, pf01, pf10, pf11;                                                    \
    PACK_P(s0, pf00, pf01);                                                           \
    PACK_P(s1, pf10, pf11);                                                           \
    __builtin_amdgcn_s_setprio(1);                                                    \
    acc[0] = __builtin_amdgcn_mfma_f32_32x32x16_bf16(vf0, pf00, acc[0], 0, 0, 0);     \
    acc[0] = __builtin_amdgcn_mfma_f32_32x32x16_bf16(vf1, pf01, acc[0], 0, 0, 0);     \
    acc[1] = __builtin_amdgcn_mfma_f32_32x32x16_bf16(vf2, pf00, acc[1], 0, 0, 0);     \
    acc[1] = __builtin_amdgcn_mfma_f32_32x32x16_bf16(vf3, pf01, acc[1], 0, 0, 0);     \
    acc[2] = __builtin_amdgcn_mfma_f32_32x32x16_bf16(vf0, pf10, acc[2], 0, 0, 0);     \
    acc[2] = __builtin_amdgcn_mfma_f32_32x32x16_bf16(vf1, pf11, acc[2], 0, 0, 0);     \
    acc[3] = __builtin_amdgcn_mfma_f32_32x32x16_bf16(vf2, pf10, acc[3], 0, 0, 0);     \
    acc[3] = __builtin_amdgcn_mfma_f32_32x32x16_bf16(vf3, pf11, acc[3], 0, 0, 0);     \
    __builtin_amdgcn_s_setprio(0);                                                    \
  } while (0)

  // prologue: stage tile 0 into buf 0
  STAGE_LOAD(sh * 1024);
  STAGE_WRITE(0);
  __syncthreads();

  for (int i = 0; i < 16; ++i) {
    if (i < 15) STAGE_LOAD(sh * 1024 + (i + 1) * 64);  // T14: load-early

    const char* Ks = Kbuf + (i & 1) * 8192;
    const int jbase = sh * 32 + i * 2;

    SUBTILE(0, jbase);
    // mid-iter STAGE_WRITE: kg long since arrived; ss=1 compute covers ds_write latency
    if (i < 15) STAGE_WRITE((i + 1) & 1);
    SUBTILE(1, jbase + 1);

    __syncthreads();
  }

  // ---- epilogue: reduce l, 2-stream merge (fixed m => plain sums), store ----
  float l0 = la0[0] + la0[1];
  float l1 = la1[0] + la1[1];
  l0 += __shfl_xor(l0, 32, 64);
  l1 += __shfl_xor(l1, 32, 64);

  float* Xa = (float*)smem + u * 4096;
  if (sh == 1) {
#pragma unroll
    for (int a = 0; a < 4; ++a)
#pragma unroll
      for (int r = 0; r < 16; ++r) Xa[(a * 16 + r) * 64 + lane] = acc[a][r];
    Xl[u][0][tl] = l0;
    Xl[u][1][tl] = l1;
  }
  __syncthreads();
  if (sh == 0) {
    float* ob = out + (size_t)bh * 64 * SEQ;
    const float inv0 = 1.0f / (l0 + Xl[u][0][tl]);
    const float inv1 = 1.0f / (l1 + Xl[u][1][tl]);
#pragma unroll
    for (int r = 0; r < 16; ++r) {
      const int c0 = (r & 3) + 8 * (r >> 2) + 4 * hi;
      const int ta = tq0 + tl, tb2 = tq0 + 32 + tl;
      ob[(size_t)c0 * SEQ + ta] = (acc[0][r] + Xa[(0 * 16 + r) * 64 + lane]) * inv0;
      ob[(size_t)(c0 + 32) * SEQ + ta] = (acc[1][r] + Xa[(1 * 16 + r) * 64 + lane]) * inv0;
      ob[(size_t)c0 * SEQ + tb2] = (acc[2][r] + Xa[(2 * 16 + r) * 64 + lane]) * inv1;
      ob[(size_t)(c0 + 32) * SEQ + tb2] = (acc[3][r] + Xa[(3 * 16 + r) * 64 + lane]) * inv1;
    }
  }
}

extern "C" void kernel_launch(void* const* d_in, const int* in_sizes, int n_in,
                              void* d_out, int out_size, void* d_ws, size_t ws_size,
                              hipStream_t stream) {
  const float* qkv = (const float*)d_in[0];
  float* out = (float*)d_out;
  u16* wsK = (u16*)d_ws;
  u16* wsV = wsK + (size_t)32 * SEQ * 64;

  prep_all<<<dim3(32, 32, 2), 256, 0, stream>>>(qkv, wsK, wsV);
  attn_kernel<<<256, 512, 0, stream>>>(qkv, wsK, wsV, out);
}